// Round 1
// baseline (509.993 us; speedup 1.0000x reference)
//
#include <hip/hip_runtime.h>
#include <hip/hip_bf16.h>
#include <math.h>

typedef __attribute__((ext_vector_type(8))) __bf16 bf16x8;
typedef __attribute__((ext_vector_type(4))) __bf16 bf16x4;
typedef __attribute__((ext_vector_type(4))) float floatx4;
typedef __attribute__((ext_vector_type(8))) unsigned short ushort8;

#define C_EMBD 1024
#define T_SEQ 2048
#define NH 16
#define HD 64

static __device__ __forceinline__ unsigned short f2b(float f) {
  __hip_bfloat16 h = __float2bfloat16(f);
  unsigned short u;
  __builtin_memcpy(&u, &h, sizeof(u));
  return u;
}

// async global->LDS, 16B per lane; lds pointer must be wave-uniform
static __device__ __forceinline__ void gload16(const void* g, void* l) {
  __builtin_amdgcn_global_load_lds(
      (__attribute__((address_space(1))) void*)(void*)g,
      (__attribute__((address_space(3))) void*)l, 16, 0, 0);
}

static __device__ __forceinline__ floatx4 mfma_bf16(bf16x8 a, bf16x8 b, floatx4 c) {
  return __builtin_amdgcn_mfma_f32_16x16x32_bf16(a, b, c, 0, 0, 0);
}

// ---------------- weight transpose: fp32 [K][N] -> bf16 [N][K] ----------------
__global__ __launch_bounds__(256) void wtrans(const float* __restrict__ in,
                                              unsigned short* __restrict__ out,
                                              int K, int N) {
  __shared__ float t[32][33];
  int n0 = blockIdx.x * 32, k0 = blockIdx.y * 32;
  int tx = threadIdx.x & 31, ty = threadIdx.x >> 5;  // ty 0..7
#pragma unroll
  for (int i = 0; i < 4; i++)
    t[ty + i * 8][tx] = in[(size_t)(k0 + ty + i * 8) * N + n0 + tx];
  __syncthreads();
#pragma unroll
  for (int i = 0; i < 4; i++)
    out[(size_t)(n0 + ty + i * 8) * K + k0 + tx] = f2b(t[tx][ty + i * 8]);
}

// ---------------- layernorm: fp32 row(1024) -> bf16 ----------------
__global__ __launch_bounds__(256) void ln_fwd(const float* __restrict__ x,
                                              const float* __restrict__ g,
                                              const float* __restrict__ bta,
                                              unsigned short* __restrict__ out) {
  int row = blockIdx.x;
  int t = threadIdx.x;
  const float4* xr = (const float4*)(x + (size_t)row * C_EMBD);
  float4 v = xr[t];
  float s = v.x + v.y + v.z + v.w;
  float ss = v.x * v.x + v.y * v.y + v.z * v.z + v.w * v.w;
#pragma unroll
  for (int m = 1; m < 64; m <<= 1) {
    s += __shfl_xor(s, m, 64);
    ss += __shfl_xor(ss, m, 64);
  }
  __shared__ float ps[8];
  int wv = t >> 6;
  if ((t & 63) == 0) { ps[wv] = s; ps[4 + wv] = ss; }
  __syncthreads();
  s = ps[0] + ps[1] + ps[2] + ps[3];
  ss = ps[4] + ps[5] + ps[6] + ps[7];
  float mu = s * (1.0f / C_EMBD);
  float var = ss * (1.0f / C_EMBD) - mu * mu;
  float rs = rsqrtf(var + 1e-5f);
  float4 gv = ((const float4*)g)[t];
  float4 bv = ((const float4*)bta)[t];
  ushort4 o;
  o.x = f2b((v.x - mu) * rs * gv.x + bv.x);
  o.y = f2b((v.y - mu) * rs * gv.y + bv.y);
  o.z = f2b((v.z - mu) * rs * gv.z + bv.z);
  o.w = f2b((v.w - mu) * rs * gv.w + bv.w);
  *(ushort4*)(out + (size_t)row * C_EMBD + t * 4) = o;
}

// ---------------- GEMM: A[M][K] bf16 x Bt[N][K] bf16 -> out[M][N] ----------------
// EP: 0 = +bias -> bf16 ; 1 = +bias+res(fp32) -> fp32 ; 2 = +bias, exact GELU -> bf16
template <int EP>
__global__ __launch_bounds__(256) void gemm_bt(const unsigned short* __restrict__ A,
                                               const unsigned short* __restrict__ Bt,
                                               const float* __restrict__ bias,
                                               const float* __restrict__ res,
                                               void* __restrict__ outv,
                                               int M, int N, int K) {
  __shared__ __align__(16) unsigned short As[128 * 32];
  __shared__ __align__(16) unsigned short Bs[128 * 32];
  const int tid = threadIdx.x;
  const int wv = tid >> 6, ln = tid & 63;
  const int quad = ln >> 4, l15 = ln & 15;
  const int wm = wv >> 1, wn = wv & 1;
  const int m0 = blockIdx.y * 128, n0 = blockIdx.x * 128;

  floatx4 acc[4][4];
#pragma unroll
  for (int i = 0; i < 4; i++)
#pragma unroll
    for (int j = 0; j < 4; j++) acc[i][j] = (floatx4)0.0f;

  const int rowA = ln >> 2;        // 0..15 within 16-row group
  const int koff = (ln & 3) * 8;   // 0,8,16,24

  for (int k0 = 0; k0 < K; k0 += 32) {
    if (k0) __syncthreads();
#pragma unroll
    for (int hh = 0; hh < 2; ++hh) {
      int r = hh * 64 + wv * 16 + rowA;
      gload16(A + (size_t)(m0 + r) * K + k0 + koff, &As[(hh * 64 + wv * 16) * 32]);
      gload16(Bt + (size_t)(n0 + r) * K + k0 + koff, &Bs[(hh * 64 + wv * 16) * 32]);
    }
    __syncthreads();
    bf16x8 af[4], bfr[4];
#pragma unroll
    for (int mi = 0; mi < 4; mi++)
      af[mi] = *(const bf16x8*)&As[(wm * 64 + mi * 16 + l15) * 32 + quad * 8];
#pragma unroll
    for (int ni = 0; ni < 4; ni++)
      bfr[ni] = *(const bf16x8*)&Bs[(wn * 64 + ni * 16 + l15) * 32 + quad * 8];
#pragma unroll
    for (int mi = 0; mi < 4; mi++)
#pragma unroll
      for (int ni = 0; ni < 4; ni++)
        acc[mi][ni] = mfma_bf16(af[mi], bfr[ni], acc[mi][ni]);
  }

#pragma unroll
  for (int mi = 0; mi < 4; mi++) {
#pragma unroll
    for (int ni = 0; ni < 4; ni++) {
      int col = n0 + wn * 64 + ni * 16 + l15;
      int rowb = m0 + wm * 64 + mi * 16 + quad * 4;
      float bc = bias[col];
#pragma unroll
      for (int r = 0; r < 4; r++) {
        float v = acc[mi][ni][r] + bc;
        size_t idx = (size_t)(rowb + r) * N + col;
        if (EP == 0) {
          ((unsigned short*)outv)[idx] = f2b(v);
        } else if (EP == 1) {
          ((float*)outv)[idx] = v + res[idx];
        } else {
          v = 0.5f * v * (1.0f + erff(v * 0.70710678118f));
          ((unsigned short*)outv)[idx] = f2b(v);
        }
      }
    }
  }
}

// ---------------- flash attention (causal), D=64 ----------------
// qkv: [B*T][3C] bf16 (q|k|v). y: [B*T][C] bf16. One block = (b, h, 64 q-rows).
__global__ __launch_bounds__(256) void attn_fwd(const unsigned short* __restrict__ qkv,
                                                unsigned short* __restrict__ y) {
  __shared__ __align__(16) unsigned short Ks[64 * 64];   // [kj][d]
  __shared__ __align__(16) unsigned short Vt[64 * 68];   // [d][kj], stride 68
  __shared__ __align__(16) unsigned short Ps[4 * 16 * 72];  // per-wave P, stride 72
  const int tid = threadIdx.x;
  const int wv = tid >> 6, ln = tid & 63;
  const int quad = ln >> 4, l15 = ln & 15;
  const int qt = blockIdx.x, h = blockIdx.y, b = blockIdx.z;

  // Q fragments (A-layout: m = l15, k = quad*8+j), rows = qt*64 + wv*16 + l15
  const unsigned short* qp =
      qkv + (size_t)(b * T_SEQ + qt * 64 + wv * 16 + l15) * (3 * C_EMBD) + h * HD;
  bf16x8 qf[2];
  qf[0] = *(const bf16x8*)(qp + quad * 8);
  qf[1] = *(const bf16x8*)(qp + 32 + quad * 8);

  float mprev[4], lsum[4], alpha[4];
  floatx4 o[4];
#pragma unroll
  for (int r = 0; r < 4; r++) { mprev[r] = -1e30f; lsum[r] = 0.0f; }
#pragma unroll
  for (int d = 0; d < 4; d++) o[d] = (floatx4)0.0f;

  unsigned short* Pw = &Ps[wv * 16 * 72];

  for (int kt = 0; kt <= qt; ++kt) {
    __syncthreads();
    // stage K [kj][d] via async 16B; V transposed manually
#pragma unroll
    for (int rd = 0; rd < 2; ++rd) {
      int row = rd * 32 + wv * 8 + (ln >> 3);
      size_t base = (size_t)(b * T_SEQ + kt * 64 + row) * (3 * C_EMBD) + h * HD + (ln & 7) * 8;
      gload16(qkv + base + C_EMBD, &Ks[(rd * 32 + wv * 8) * 64]);
      ushort8 v8 = *(const ushort8*)(qkv + base + 2 * C_EMBD);
#pragma unroll
      for (int j = 0; j < 8; j++) Vt[((ln & 7) * 8 + j) * 68 + row] = v8[j];
    }
    __syncthreads();

    // S = Q K^T (per wave: 16q x 64k)
    floatx4 s[4];
#pragma unroll
    for (int nt = 0; nt < 4; nt++) s[nt] = (floatx4)0.0f;
#pragma unroll
    for (int nt = 0; nt < 4; nt++)
#pragma unroll
      for (int kc = 0; kc < 2; kc++) {
        bf16x8 kf = *(const bf16x8*)&Ks[(nt * 16 + l15) * 64 + kc * 32 + quad * 8];
        s[nt] = mfma_bf16(qf[kc], kf, s[nt]);
      }

    const bool diag = (kt == qt);
#pragma unroll
    for (int nt = 0; nt < 4; nt++)
#pragma unroll
      for (int r = 0; r < 4; r++) {
        float sv = s[nt][r] * 0.125f;
        if (diag && (nt * 16 + l15 > wv * 16 + quad * 4 + r)) sv = -1e30f;
        s[nt][r] = sv;
      }

    // online softmax row stats (row = quad*4+r, 64 cols across 16 lanes x 4 nt)
#pragma unroll
    for (int r = 0; r < 4; r++) {
      float rm = fmaxf(fmaxf(s[0][r], s[1][r]), fmaxf(s[2][r], s[3][r]));
      rm = fmaxf(rm, __shfl_xor(rm, 1, 64));
      rm = fmaxf(rm, __shfl_xor(rm, 2, 64));
      rm = fmaxf(rm, __shfl_xor(rm, 4, 64));
      rm = fmaxf(rm, __shfl_xor(rm, 8, 64));
      float mn = fmaxf(mprev[r], rm);
      alpha[r] = __expf(mprev[r] - mn);
      mprev[r] = mn;
    }
    float psum[4] = {0.f, 0.f, 0.f, 0.f};
#pragma unroll
    for (int nt = 0; nt < 4; nt++)
#pragma unroll
      for (int r = 0; r < 4; r++) {
        float p = __expf(s[nt][r] - mprev[r]);
        psum[r] += p;
        Pw[(quad * 4 + r) * 72 + nt * 16 + l15] = f2b(p);  // C-layout -> LDS
      }
#pragma unroll
    for (int r = 0; r < 4; r++) {
      float rs = psum[r];
      rs += __shfl_xor(rs, 1, 64);
      rs += __shfl_xor(rs, 2, 64);
      rs += __shfl_xor(rs, 4, 64);
      rs += __shfl_xor(rs, 8, 64);
      lsum[r] = lsum[r] * alpha[r] + rs;
      o[0][r] *= alpha[r]; o[1][r] *= alpha[r];
      o[2][r] *= alpha[r]; o[3][r] *= alpha[r];
    }

    // PV: A = P (re-read in A-layout), B = V^T from Vt
    bf16x8 pf[2];
    pf[0] = *(const bf16x8*)&Pw[l15 * 72 + quad * 8];
    pf[1] = *(const bf16x8*)&Pw[l15 * 72 + 32 + quad * 8];
#pragma unroll
    for (int dt = 0; dt < 4; ++dt)
#pragma unroll
      for (int kc = 0; kc < 2; kc++) {
        bf16x4 v0 = *(const bf16x4*)&Vt[(dt * 16 + l15) * 68 + kc * 32 + quad * 8];
        bf16x4 v1 = *(const bf16x4*)&Vt[(dt * 16 + l15) * 68 + kc * 32 + quad * 8 + 4];
        bf16x8 vf = __builtin_shufflevector(v0, v1, 0, 1, 2, 3, 4, 5, 6, 7);
        o[dt] = mfma_bf16(pf[kc], vf, o[dt]);
      }
  }

#pragma unroll
  for (int dt = 0; dt < 4; ++dt)
#pragma unroll
    for (int r = 0; r < 4; r++) {
      float val = o[dt][r] / lsum[r];
      size_t row = (size_t)(b * T_SEQ + qt * 64 + wv * 16 + quad * 4 + r);
      y[row * C_EMBD + h * HD + dt * 16 + l15] = f2b(val);
    }
}

extern "C" void kernel_launch(void* const* d_in, const int* in_sizes, int n_in,
                              void* d_out, int out_size, void* d_ws, size_t ws_size,
                              hipStream_t stream) {
  (void)in_sizes; (void)n_in; (void)out_size; (void)ws_size;
  const float* x      = (const float*)d_in[0];
  const float* ln1_g  = (const float*)d_in[1];
  const float* ln1_b  = (const float*)d_in[2];
  const float* w_attn = (const float*)d_in[3];
  const float* b_attn = (const float*)d_in[4];
  const float* w_proj = (const float*)d_in[5];
  const float* b_proj = (const float*)d_in[6];
  const float* ln2_g  = (const float*)d_in[7];
  const float* ln2_b  = (const float*)d_in[8];
  const float* w_fc   = (const float*)d_in[9];
  const float* b_fc   = (const float*)d_in[10];
  const float* w_fc2  = (const float*)d_in[11];
  const float* b_fc2  = (const float*)d_in[12];
  float* out = (float*)d_out;  // also serves as x1 (post-attention residual)

  char* ws = (char*)d_ws;
  unsigned short* wat  = (unsigned short*)ws; ws += (size_t)3072 * 1024 * 2;
  unsigned short* wpt  = (unsigned short*)ws; ws += (size_t)1024 * 1024 * 2;
  unsigned short* wft  = (unsigned short*)ws; ws += (size_t)4096 * 1024 * 2;
  unsigned short* wf2t = (unsigned short*)ws; ws += (size_t)1024 * 4096 * 2;
  unsigned short* xn   = (unsigned short*)ws; ws += (size_t)4096 * 1024 * 2;  // reused for ln2
  unsigned short* qkv  = (unsigned short*)ws; ws += (size_t)4096 * 3072 * 2;
  unsigned short* yat  = (unsigned short*)ws; ws += (size_t)4096 * 1024 * 2;
  unsigned short* hbuf = (unsigned short*)ws; ws += (size_t)4096 * 4096 * 2;

  // weights -> bf16 [N][K]
  wtrans<<<dim3(3072 / 32, 1024 / 32), 256, 0, stream>>>(w_attn, wat, 1024, 3072);
  wtrans<<<dim3(1024 / 32, 1024 / 32), 256, 0, stream>>>(w_proj, wpt, 1024, 1024);
  wtrans<<<dim3(4096 / 32, 1024 / 32), 256, 0, stream>>>(w_fc, wft, 1024, 4096);
  wtrans<<<dim3(1024 / 32, 4096 / 32), 256, 0, stream>>>(w_fc2, wf2t, 4096, 1024);

  ln_fwd<<<4096, 256, 0, stream>>>(x, ln1_g, ln1_b, xn);
  gemm_bt<0><<<dim3(3072 / 128, 4096 / 128), 256, 0, stream>>>(
      xn, wat, b_attn, nullptr, qkv, 4096, 3072, 1024);
  attn_fwd<<<dim3(T_SEQ / 64, NH, 2), 256, 0, stream>>>(qkv, yat);
  gemm_bt<1><<<dim3(1024 / 128, 4096 / 128), 256, 0, stream>>>(
      yat, wpt, b_proj, x, out, 4096, 1024, 1024);
  ln_fwd<<<4096, 256, 0, stream>>>(out, ln2_g, ln2_b, xn);
  gemm_bt<2><<<dim3(4096 / 128, 4096 / 128), 256, 0, stream>>>(
      xn, wft, b_fc, nullptr, hbuf, 4096, 4096, 1024);
  gemm_bt<1><<<dim3(1024 / 128, 4096 / 128), 256, 0, stream>>>(
      hbuf, wf2t, b_fc2, out, out, 4096, 1024, 4096);
}

// Round 2
// 384.459 us; speedup vs baseline: 1.3265x; 1.3265x over previous
//
#include <hip/hip_runtime.h>
#include <hip/hip_bf16.h>
#include <math.h>

typedef __attribute__((ext_vector_type(8))) __bf16 bf16x8;
typedef __attribute__((ext_vector_type(4))) float floatx4;
typedef __attribute__((ext_vector_type(8))) unsigned short ushort8;

#define C_EMBD 1024
#define T_SEQ 2048
#define NH 16
#define HD 64

static __device__ __forceinline__ unsigned short f2b(float f) {
  __hip_bfloat16 h = __float2bfloat16(f);
  unsigned short u;
  __builtin_memcpy(&u, &h, sizeof(u));
  return u;
}
static __device__ __forceinline__ float b2f(unsigned short u) {
  unsigned int b = ((unsigned int)u) << 16;
  float f;
  __builtin_memcpy(&f, &b, sizeof(f));
  return f;
}

// async global->LDS, 16B per lane; lds base wave-uniform, lane i -> base + i*16
static __device__ __forceinline__ void gload16(const void* g, void* l) {
  __builtin_amdgcn_global_load_lds(
      (__attribute__((address_space(1))) void*)(void*)g,
      (__attribute__((address_space(3))) void*)l, 16, 0, 0);
}

static __device__ __forceinline__ floatx4 mfma_bf16(bf16x8 a, bf16x8 b, floatx4 c) {
  return __builtin_amdgcn_mfma_f32_16x16x32_bf16(a, b, c, 0, 0, 0);
}

// ---------------- weight transpose: fp32 [K][N] -> bf16 [N][K] ----------------
__global__ __launch_bounds__(256) void wtrans(const float* __restrict__ in,
                                              unsigned short* __restrict__ out,
                                              int K, int N) {
  __shared__ float t[32][33];
  int n0 = blockIdx.x * 32, k0 = blockIdx.y * 32;
  int tx = threadIdx.x & 31, ty = threadIdx.x >> 5;
#pragma unroll
  for (int i = 0; i < 4; i++)
    t[ty + i * 8][tx] = in[(size_t)(k0 + ty + i * 8) * N + n0 + tx];
  __syncthreads();
#pragma unroll
  for (int i = 0; i < 4; i++)
    out[(size_t)(n0 + ty + i * 8) * K + k0 + tx] = f2b(t[tx][ty + i * 8]);
}

// ---------------- layernorm: fp32 row(1024) -> bf16 ----------------
__global__ __launch_bounds__(256) void ln_fwd(const float* __restrict__ x,
                                              const float* __restrict__ g,
                                              const float* __restrict__ bta,
                                              unsigned short* __restrict__ out) {
  int row = blockIdx.x;
  int t = threadIdx.x;
  const float4* xr = (const float4*)(x + (size_t)row * C_EMBD);
  float4 v = xr[t];
  float s = v.x + v.y + v.z + v.w;
  float ss = v.x * v.x + v.y * v.y + v.z * v.z + v.w * v.w;
#pragma unroll
  for (int m = 1; m < 64; m <<= 1) {
    s += __shfl_xor(s, m, 64);
    ss += __shfl_xor(ss, m, 64);
  }
  __shared__ float ps[8];
  int wv = t >> 6;
  if ((t & 63) == 0) { ps[wv] = s; ps[4 + wv] = ss; }
  __syncthreads();
  s = ps[0] + ps[1] + ps[2] + ps[3];
  ss = ps[4] + ps[5] + ps[6] + ps[7];
  float mu = s * (1.0f / C_EMBD);
  float var = ss * (1.0f / C_EMBD) - mu * mu;
  float rs = rsqrtf(var + 1e-5f);
  float4 gv = ((const float4*)g)[t];
  float4 bv = ((const float4*)bta)[t];
  ushort4 o;
  o.x = f2b((v.x - mu) * rs * gv.x + bv.x);
  o.y = f2b((v.y - mu) * rs * gv.y + bv.y);
  o.z = f2b((v.z - mu) * rs * gv.z + bv.z);
  o.w = f2b((v.w - mu) * rs * gv.w + bv.w);
  *(ushort4*)(out + (size_t)row * C_EMBD + t * 4) = o;
}

// ---------------- GEMM: A[M][K] bf16 x Bt[N][K] bf16 -> out[M][N] ----------------
// Tile: (MI*32) x 128, 4 waves in 2x2 (MI=4) or per-wave (MI*16)x64.
// EP: 1 = +bias+res(fp32) -> fp32 ; 2 = +bias, exact GELU -> bf16 ;
//     3 = QKV split: cols<2048 -> bf16 qkv[row][N]; cols>=2048 -> V^T[b,h,d,t] bf16
template <int EP, int MI>
__global__ __launch_bounds__(256) void gemm_bt(const unsigned short* __restrict__ A,
                                               const unsigned short* __restrict__ Bt,
                                               const float* __restrict__ bias,
                                               const float* __restrict__ res,
                                               void* __restrict__ outv,
                                               unsigned short* __restrict__ vt,
                                               int M, int N, int K) {
  __shared__ __align__(16) unsigned short As[MI * 32 * 32];
  __shared__ __align__(16) unsigned short Bs[128 * 32];
  const int tid = threadIdx.x;
  const int wv = tid >> 6, ln = tid & 63;
  const int quad = ln >> 4, l15 = ln & 15;
  const int wm = wv >> 1, wn = wv & 1;
  const int m0 = blockIdx.y * (MI * 32), n0 = blockIdx.x * 128;

  floatx4 acc[MI][4];
#pragma unroll
  for (int i = 0; i < MI; i++)
#pragma unroll
    for (int j = 0; j < 4; j++) acc[i][j] = (floatx4)0.0f;

  const int rowA = ln >> 2;
  const int koff = (ln & 3) * 8;

  for (int k0 = 0; k0 < K; k0 += 32) {
    if (k0) __syncthreads();
#pragma unroll
    for (int hh = 0; hh < MI / 2; ++hh) {
      int r = hh * 64 + wv * 16 + rowA;
      gload16(A + (size_t)(m0 + r) * K + k0 + koff, &As[(hh * 64 + wv * 16) * 32]);
    }
#pragma unroll
    for (int hh = 0; hh < 2; ++hh) {
      int r = hh * 64 + wv * 16 + rowA;
      gload16(Bt + (size_t)(n0 + r) * K + k0 + koff, &Bs[(hh * 64 + wv * 16) * 32]);
    }
    __syncthreads();
    bf16x8 af[MI], bfr[4];
#pragma unroll
    for (int mi = 0; mi < MI; mi++)
      af[mi] = *(const bf16x8*)&As[(wm * (MI * 16) + mi * 16 + l15) * 32 + quad * 8];
#pragma unroll
    for (int ni = 0; ni < 4; ni++)
      bfr[ni] = *(const bf16x8*)&Bs[(wn * 64 + ni * 16 + l15) * 32 + quad * 8];
#pragma unroll
    for (int mi = 0; mi < MI; mi++)
#pragma unroll
      for (int ni = 0; ni < 4; ni++)
        acc[mi][ni] = mfma_bf16(af[mi], bfr[ni], acc[mi][ni]);
  }

#pragma unroll
  for (int mi = 0; mi < MI; mi++) {
#pragma unroll
    for (int ni = 0; ni < 4; ni++) {
      int col = n0 + wn * 64 + ni * 16 + l15;
      int rowb = m0 + wm * (MI * 16) + mi * 16 + quad * 4;
      float bc = bias[col];
      if (EP == 1) {
#pragma unroll
        for (int r = 0; r < 4; r++) {
          size_t idx = (size_t)(rowb + r) * N + col;
          ((float*)outv)[idx] = acc[mi][ni][r] + bc + res[idx];
        }
      } else if (EP == 2) {
#pragma unroll
        for (int r = 0; r < 4; r++) {
          float v = acc[mi][ni][r] + bc;
          v = 0.5f * v * (1.0f + erff(v * 0.70710678118f));
          ((unsigned short*)outv)[(size_t)(rowb + r) * N + col] = f2b(v);
        }
      } else {  // EP == 3
        if (col < 2048) {
#pragma unroll
          for (int r = 0; r < 4; r++)
            ((unsigned short*)outv)[(size_t)(rowb + r) * N + col] =
                f2b(acc[mi][ni][r] + bc);
        } else {
          int dall = col - 2048;
          int hh2 = dall >> 6, dd = dall & 63;
          int bq = rowb >> 11, t0 = rowb & 2047;
          __align__(8) unsigned short pk[4];
#pragma unroll
          for (int r = 0; r < 4; r++) pk[r] = f2b(acc[mi][ni][r] + bc);
          *(ushort4*)&vt[(size_t)((bq * NH + hh2) * HD + dd) * T_SEQ + t0] =
              *(const ushort4*)pk;
        }
      }
    }
  }
}

// ---------------- flash attention (causal), D=64, operand-swapped ----------------
// qkv: [B*T][3C] bf16 (q|k cols 0..2047; v third unused). vt: V^T [B,H,64,T] bf16.
// One block = (pair, h, b); handles q-tiles {pair, 31-pair} (33 kt-iters total).
// Per lane: one q-row (l15 + wv*16). Static-max log2-domain softmax.
__global__ __launch_bounds__(256) void attn_fwd(const unsigned short* __restrict__ qkv,
                                                const unsigned short* __restrict__ vt,
                                                unsigned short* __restrict__ y) {
  __shared__ __align__(16) unsigned short Ks[64 * 64];  // [k][d], 16B-chunk xor-swizzled
  __shared__ __align__(16) unsigned short Vs[64 * 64];  // [d][k], same swizzle
  __shared__ __align__(16) unsigned short Ps[4 * 16 * 72];  // per-wave P[qrow][k]
  const int tid = threadIdx.x;
  const int wv = tid >> 6, ln = tid & 63;
  const int quad = ln >> 4, l15 = ln & 15;
  const int pair = blockIdx.x, h = blockIdx.y, b = blockIdx.z;
  unsigned short* Pw = &Ps[wv * 16 * 72];

  const unsigned short* kbase = qkv + (size_t)b * T_SEQ * 3072 + 1024 + h * HD;
  const unsigned short* vbase = vt + (size_t)(b * NH + h) * HD * T_SEQ;

  // staging geometry: slot S = wv*128 + g*64 + ln; row=S>>3, chunk=(S&7)^(row&7)
  int koffs[2], voffs[2], ldst[2];
#pragma unroll
  for (int g = 0; g < 2; g++) {
    int S = wv * 128 + g * 64 + ln;
    int r = S >> 3;
    int c = (S & 7) ^ (r & 7);
    koffs[g] = r * 3072 + c * 8;
    voffs[g] = r * T_SEQ + c * 8;
    ldst[g] = wv * 1024 + g * 512;
  }

  for (int ph = 0; ph < 2; ++ph) {
    const int qt = ph ? (31 - pair) : pair;
    // Q fragments, pre-scaled by 1/8 * log2(e) (log2-domain softmax)
    const unsigned short* qp =
        qkv + (size_t)(b * T_SEQ + qt * 64 + wv * 16 + l15) * 3072 + h * HD;
    bf16x8 qf[2];
#pragma unroll
    for (int kc = 0; kc < 2; kc++) {
      ushort8 u = *(const ushort8*)(qp + kc * 32 + quad * 8);
      union { ushort8 u; bf16x8 v; } cv;
#pragma unroll
      for (int j = 0; j < 8; j++) cv.u[j] = f2b(b2f(u[j]) * 0.18033688f);
      qf[kc] = cv.v;
    }

    floatx4 o[4];
#pragma unroll
    for (int dt = 0; dt < 4; dt++) o[dt] = (floatx4)0.0f;
    float lacc = 0.0f;

    auto step = [&](int kt, bool diag) {
      __syncthreads();
#pragma unroll
      for (int g = 0; g < 2; g++) {
        gload16(kbase + (size_t)(kt * 64) * 3072 + koffs[g], &Ks[ldst[g]]);
        gload16(vbase + kt * 64 + voffs[g], &Vs[ldst[g]]);
      }
      __syncthreads();

      // S^T = K . Q^T : per lane qrow=l15(+wv*16), kidx = nt*16 + quad*4 + r
      floatx4 s[4];
#pragma unroll
      for (int nt = 0; nt < 4; nt++) s[nt] = (floatx4)0.0f;
#pragma unroll
      for (int nt = 0; nt < 4; nt++)
#pragma unroll
        for (int kc = 0; kc < 2; kc++) {
          bf16x8 kf = *(const bf16x8*)
              &Ks[(nt * 16 + l15) * 64 + (((kc * 4 + quad) ^ (l15 & 7)) * 8)];
          s[nt] = mfma_bf16(kf, qf[kc], s[nt]);
        }

      float psum = 0.0f;
#pragma unroll
      for (int nt = 0; nt < 4; nt++) {
        __align__(8) unsigned short pk[4];
#pragma unroll
        for (int r = 0; r < 4; r++) {
          float sv = s[nt][r];
          if (diag && (nt * 16 + quad * 4 + r > wv * 16 + l15)) sv = -1e30f;
          float p = exp2f(sv - 12.0f);
          psum += p;
          pk[r] = f2b(p);
        }
        *(ushort4*)&Pw[l15 * 72 + nt * 16 + quad * 4] = *(const ushort4*)pk;
      }
      lacc += psum;

      // O^T = V^T . P : A-frag rows d, B-frag = P rows qrow=l15
      bf16x8 pf0 = *(const bf16x8*)&Pw[l15 * 72 + quad * 8];
      bf16x8 pf1 = *(const bf16x8*)&Pw[l15 * 72 + 32 + quad * 8];
#pragma unroll
      for (int dt = 0; dt < 4; dt++) {
        bf16x8 vf0 = *(const bf16x8*)
            &Vs[(dt * 16 + l15) * 64 + ((quad ^ (l15 & 7)) * 8)];
        bf16x8 vf1 = *(const bf16x8*)
            &Vs[(dt * 16 + l15) * 64 + (((4 + quad) ^ (l15 & 7)) * 8)];
        o[dt] = mfma_bf16(vf0, pf0, o[dt]);
        o[dt] = mfma_bf16(vf1, pf1, o[dt]);
      }
    };

    for (int kt = 0; kt < qt; ++kt) step(kt, false);
    step(qt, true);

    lacc += __shfl_xor(lacc, 16, 64);
    lacc += __shfl_xor(lacc, 32, 64);
    float rinv = 1.0f / lacc;
#pragma unroll
    for (int dt = 0; dt < 4; dt++) {
      __align__(8) unsigned short ov[4];
#pragma unroll
      for (int r = 0; r < 4; r++) ov[r] = f2b(o[dt][r] * rinv);
      *(ushort4*)&y[(size_t)(b * T_SEQ + qt * 64 + wv * 16 + l15) * C_EMBD +
                    h * HD + dt * 16 + quad * 4] = *(const ushort4*)ov;
    }
  }
}

extern "C" void kernel_launch(void* const* d_in, const int* in_sizes, int n_in,
                              void* d_out, int out_size, void* d_ws, size_t ws_size,
                              hipStream_t stream) {
  (void)in_sizes; (void)n_in; (void)out_size; (void)ws_size;
  const float* x      = (const float*)d_in[0];
  const float* ln1_g  = (const float*)d_in[1];
  const float* ln1_b  = (const float*)d_in[2];
  const float* w_attn = (const float*)d_in[3];
  const float* b_attn = (const float*)d_in[4];
  const float* w_proj = (const float*)d_in[5];
  const float* b_proj = (const float*)d_in[6];
  const float* ln2_g  = (const float*)d_in[7];
  const float* ln2_b  = (const float*)d_in[8];
  const float* w_fc   = (const float*)d_in[9];
  const float* b_fc   = (const float*)d_in[10];
  const float* w_fc2  = (const float*)d_in[11];
  const float* b_fc2  = (const float*)d_in[12];
  float* out = (float*)d_out;  // also serves as x1 (post-attention residual)

  char* ws = (char*)d_ws;
  unsigned short* wat  = (unsigned short*)ws; ws += (size_t)3072 * 1024 * 2;
  unsigned short* wpt  = (unsigned short*)ws; ws += (size_t)1024 * 1024 * 2;
  unsigned short* wft  = (unsigned short*)ws; ws += (size_t)4096 * 1024 * 2;
  unsigned short* wf2t = (unsigned short*)ws; ws += (size_t)1024 * 4096 * 2;
  unsigned short* xn   = (unsigned short*)ws; ws += (size_t)4096 * 1024 * 2;  // ln1/ln2 out
  unsigned short* qkv  = (unsigned short*)ws; ws += (size_t)4096 * 3072 * 2;
  unsigned short* yat  = (unsigned short*)ws; ws += (size_t)4096 * 1024 * 2;
  unsigned short* hbuf = (unsigned short*)ws; ws += (size_t)4096 * 4096 * 2;
  // V^T (8 MB) aliases hbuf (32 MB): vt live QKV-gemm -> attn; hbuf live FC -> FC2.
  unsigned short* vt = hbuf;

  wtrans<<<dim3(3072 / 32, 1024 / 32), 256, 0, stream>>>(w_attn, wat, 1024, 3072);
  wtrans<<<dim3(1024 / 32, 1024 / 32), 256, 0, stream>>>(w_proj, wpt, 1024, 1024);
  wtrans<<<dim3(4096 / 32, 1024 / 32), 256, 0, stream>>>(w_fc, wft, 1024, 4096);
  wtrans<<<dim3(1024 / 32, 4096 / 32), 256, 0, stream>>>(w_fc2, wf2t, 4096, 1024);

  ln_fwd<<<4096, 256, 0, stream>>>(x, ln1_g, ln1_b, xn);
  gemm_bt<3, 4><<<dim3(24, 32), 256, 0, stream>>>(
      xn, wat, b_attn, nullptr, qkv, vt, 4096, 3072, 1024);
  attn_fwd<<<dim3(16, NH, 2), 256, 0, stream>>>(qkv, vt, yat);
  gemm_bt<1, 2><<<dim3(8, 64), 256, 0, stream>>>(
      yat, wpt, b_proj, x, out, nullptr, 4096, 1024, 1024);
  ln_fwd<<<4096, 256, 0, stream>>>(out, ln2_g, ln2_b, xn);
  gemm_bt<2, 4><<<dim3(32, 32), 256, 0, stream>>>(
      xn, wft, b_fc, nullptr, hbuf, nullptr, 4096, 4096, 1024);
  gemm_bt<1, 2><<<dim3(8, 64), 256, 0, stream>>>(
      hbuf, wf2t, b_fc2, out, out, nullptr, 4096, 1024, 4096);
}